// Round 4
// baseline (326.353 us; speedup 1.0000x reference)
//
#include <hip/hip_runtime.h>

// StainNormalization v4: persistent blocks + register-staged software pipeline.
//
// out[d] = min(exp2(sum_c log2(x_c+1e-6) * (M[c][d]*gamma[d]) - beta[d]/ln2), 1)
// (exp2 >= 0 always, so the lower clamp is free)
//
// v3 (barrier-free wave-private LDS staging) = ~80us inferred (~5.0 TB/s) vs
// 64us copy floor. Post-mortem: barriers were NOT the cost (-1us). Remaining
// theory: MLP. Each short-lived block issues 3KB of loads per wave ONCE, then
// goes quiet (LDS+compute+store+endpgm). Load-wait duty cycle ~5% x 32 waves
// ~= 1.5 waves in load-state per CU -- borderline for covering ~900cy HBM
// latency. Plus 16384 block prologues (kernarg+param loads) on the serial path.
//
// v4: grid = min(2048, nchunks) persistent blocks; each wave loops over chunks
// stride gridDim. Pipeline per iteration:
//   1. ds_write chunk n regs -> wave-private LDS   (vmcnt(3): 3 stores in flight)
//   2. issue 3 nontemporal loads chunk n+1 -> SAME regs (WAR, in-order safe)
//   3. pixel-gather ds_reads, compute, result ds_writes, linear ds_reads,
//      3 nontemporal stores of chunk n            (next loads fly under all of it)
// Steady state: every wave holds 3KB of loads in flight continuously
// (32 waves x 3KB = 96KB/CU >> 4.6KB Little's-law requirement), vmcnt never
// drains to 0 in the loop, prologue amortized over ~8 chunks.
//
// Swizzle swz(k) = k + (k>>3) (pad slot per 8): linear-side (k = lane+64i) and
// pixel-side (k = 3*lane+j) b128 accesses each land 8 lanes per bank-group ->
// conflict-free-equivalent (verified: SQ_LDS_BANK_CONFLICT = 0 in v2.1/v3).
// Wave window stride 216 (== 0 mod 8) preserves the structure.
// LDS = 4*216*16B = 13.8 KiB -> 8 blocks/CU (waves-limited).

typedef float f4 __attribute__((ext_vector_type(4)));

constexpr int BLOCK = 256;
constexpr int WSLOTS = 192;                    // float4 slots per wave (64 lanes * 3)
constexpr int WPAD = WSLOTS + WSLOTS / 8;      // 216 with pad slots
constexpr int LDS_SLOTS = 4 * WPAD;            // 864
constexpr int SLOTS = BLOCK * 3;               // 768 float4 slots per chunk
constexpr int PIXB = 1024;                     // pixels per chunk
constexpr int MAXGRID = 2048;                  // 256 CU x 8 blocks

__device__ __forceinline__ int swz(int k) { return k + (k >> 3); }

__global__ __launch_bounds__(BLOCK) void stain_norm_kernel(
    const float* __restrict__ x,
    const float* __restrict__ Mp,     // 3x3 row-major M[c*3+d]
    const float* __restrict__ gp,     // gamma[3]
    const float* __restrict__ bp,     // beta[3]
    float* __restrict__ out,
    int npix, int nchunks)
{
    __shared__ f4 lds[LDS_SLOTS];

    // Uniform parameter loads (broadcast, cached; SGPR-resident constants)
    const float g0 = gp[0], g1 = gp[1], g2 = gp[2];
    const float A00 = Mp[0] * g0, A01 = Mp[1] * g1, A02 = Mp[2] * g2;
    const float A10 = Mp[3] * g0, A11 = Mp[4] * g1, A12 = Mp[5] * g2;
    const float A20 = Mp[6] * g0, A21 = Mp[7] * g1, A22 = Mp[8] * g2;
    const float INV_LN2 = 1.4426950408889634f;
    const float c0 = -bp[0] * INV_LN2;
    const float c1 = -bp[1] * INV_LN2;
    const float c2 = -bp[2] * INV_LN2;
    const float EPS = 1e-6f;

    const int t    = threadIdx.x;
    const int wid  = t >> 6;
    const int lane = t & 63;
    const int stride = gridDim.x;

    f4* __restrict__ wlds = lds + wid * WPAD;            // wave-private window
    const f4* __restrict__ xq = reinterpret_cast<const f4*>(x);
    f4* __restrict__ oq       = reinterpret_cast<f4*>(out);
    const int base_off = wid * WSLOTS + lane;            // + chunk*SLOTS + i*64

    int c = blockIdx.x;
    f4 r0, r1, r2;
    if (c < nchunks) {
        // pipeline prologue: issue first chunk's loads
        const f4* __restrict__ p = xq + (size_t)c * SLOTS + base_off;
        r0 = __builtin_nontemporal_load(p);
        r1 = __builtin_nontemporal_load(p + 64);
        r2 = __builtin_nontemporal_load(p + 128);
    }

    while (c < nchunks) {
        // ---- stage current chunk regs -> swizzled LDS (waits vmcnt for r*) ----
        wlds[swz(lane)]       = r0;
        wlds[swz(lane + 64)]  = r1;
        wlds[swz(lane + 128)] = r2;

        // ---- issue next chunk's loads into the same regs (in flight below) ----
        const int cn = c + stride;
        if (cn < nchunks) {
            const f4* __restrict__ p = xq + (size_t)cn * SLOTS + base_off;
            r0 = __builtin_nontemporal_load(p);
            r1 = __builtin_nontemporal_load(p + 64);
            r2 = __builtin_nontemporal_load(p + 128);
        }

        // ---- gather 4 whole pixels (12 floats) from LDS, compute ----
        float f[12];
#pragma unroll
        for (int j = 0; j < 3; ++j) {
            f4 v = wlds[swz(3 * lane + j)];
            f[4 * j + 0] = v.x; f[4 * j + 1] = v.y;
            f[4 * j + 2] = v.z; f[4 * j + 3] = v.w;
        }

        float o[12];
#pragma unroll
        for (int j = 0; j < 4; ++j) {
            const float l0 = __builtin_amdgcn_logf(f[3 * j + 0] + EPS);
            const float l1 = __builtin_amdgcn_logf(f[3 * j + 1] + EPS);
            const float l2 = __builtin_amdgcn_logf(f[3 * j + 2] + EPS);
            o[3 * j + 0] = fminf(__builtin_amdgcn_exp2f(fmaf(l0, A00, fmaf(l1, A10, fmaf(l2, A20, c0)))), 1.0f);
            o[3 * j + 1] = fminf(__builtin_amdgcn_exp2f(fmaf(l0, A01, fmaf(l1, A11, fmaf(l2, A21, c1)))), 1.0f);
            o[3 * j + 2] = fminf(__builtin_amdgcn_exp2f(fmaf(l0, A02, fmaf(l1, A12, fmaf(l2, A22, c2)))), 1.0f);
        }

        // ---- results back to the same slots (same wave, lgkmcnt-ordered) ----
#pragma unroll
        for (int j = 0; j < 3; ++j) {
            f4 v;
            v.x = o[4 * j + 0]; v.y = o[4 * j + 1];
            v.z = o[4 * j + 2]; v.w = o[4 * j + 3];
            wlds[swz(3 * lane + j)] = v;
        }

        // ---- linear ds_reads -> contiguous global stores ----
        f4 s0 = wlds[swz(lane)];
        f4 s1 = wlds[swz(lane + 64)];
        f4 s2 = wlds[swz(lane + 128)];
        f4* __restrict__ q = oq + (size_t)c * SLOTS + base_off;
        __builtin_nontemporal_store(s0, q);
        __builtin_nontemporal_store(s1, q + 64);
        __builtin_nontemporal_store(s2, q + 128);

        c = cn;
    }

    // ---- tail pixels (npix % 1024; empty for the bench shape) ----
    if (blockIdx.x == 0) {
        for (int qq = nchunks * PIXB + t; qq < npix; qq += BLOCK) {
            const float l0 = __builtin_amdgcn_logf(x[3 * qq + 0] + EPS);
            const float l1 = __builtin_amdgcn_logf(x[3 * qq + 1] + EPS);
            const float l2 = __builtin_amdgcn_logf(x[3 * qq + 2] + EPS);
            out[3 * qq + 0] = fminf(__builtin_amdgcn_exp2f(fmaf(l0, A00, fmaf(l1, A10, fmaf(l2, A20, c0)))), 1.0f);
            out[3 * qq + 1] = fminf(__builtin_amdgcn_exp2f(fmaf(l0, A01, fmaf(l1, A11, fmaf(l2, A21, c1)))), 1.0f);
            out[3 * qq + 2] = fminf(__builtin_amdgcn_exp2f(fmaf(l0, A02, fmaf(l1, A12, fmaf(l2, A22, c2)))), 1.0f);
        }
    }
}

extern "C" void kernel_launch(void* const* d_in, const int* in_sizes, int n_in,
                              void* d_out, int out_size, void* d_ws, size_t ws_size,
                              hipStream_t stream) {
    const float* x     = (const float*)d_in[0];
    const float* M     = (const float*)d_in[1];
    const float* gamma = (const float*)d_in[2];
    const float* beta  = (const float*)d_in[3];
    float* out = (float*)d_out;

    const int n = in_sizes[0];        // total floats (B*H*W*3)
    const int npix = n / 3;           // pixels
    const int nchunks = npix / PIXB;  // full 1024-pixel chunks
    int grid = nchunks < MAXGRID ? nchunks : MAXGRID;
    if (grid < 1) grid = 1;           // tail-only degenerate case

    stain_norm_kernel<<<grid, BLOCK, 0, stream>>>(x, M, gamma, beta, out, npix, nchunks);
}